// Round 1
// baseline (751.398 us; speedup 1.0000x reference)
//
#include <hip/hip_runtime.h>

// LinearSpatialAttention: B=16, C=64, N=H*W=65536, DIM=8
// qkv rows: [0..7]=q, [8..15]=k, [16..23]=v
// kv[b][d][e] = sum_n vpad[d,n]*k[e,n]  (d=0..8, vpad[8]=1; e=0..7)
// A[b][c][e]  = sum_d proj_w[c][d]*kv[b][d][e]
// out[b][c][n] = x[b][c][n] + (1/den)*sum_e A[c,e]*q[e,n],
//   den = eps + sum_e kv[8,e]*q[e,n]

#define N_PIX 65536
#define C_CH 64
#define EPS_F 1e-6f

__global__ __launch_bounds__(256) void kv_reduce_kernel(
    const float* __restrict__ x, const float* __restrict__ qkv_w,
    float* __restrict__ kv_g)
{
    const int b = blockIdx.x >> 6;      // 64 blocks per batch
    const int chunk = blockIdx.x & 63;  // 1024 pixels per chunk
    const int tid = threadIdx.x;
    const float* xb = x + (size_t)b * C_CH * N_PIX;

    float kvf[72];
#pragma unroll
    for (int i = 0; i < 72; ++i) kvf[i] = 0.f;

#pragma unroll
    for (int pass = 0; pass < 2; ++pass) {
        const int n = chunk * 1024 + pass * 512 + tid * 2;
        float ax[16], ay[16];
#pragma unroll
        for (int o = 0; o < 16; ++o) { ax[o] = 0.f; ay[o] = 0.f; }
#pragma unroll 8
        for (int c = 0; c < 64; ++c) {
            const float2 xv =
                *reinterpret_cast<const float2*>(xb + (size_t)c * N_PIX + n);
#pragma unroll
            for (int o = 0; o < 16; ++o) {
                const float w = qkv_w[(8 + o) * 64 + c];  // uniform -> s_load
                ax[o] = fmaf(w, xv.x, ax[o]);
                ay[o] = fmaf(w, xv.y, ay[o]);
            }
        }
        // accumulate kv outer products for the two pixels
#pragma unroll
        for (int e = 0; e < 8; ++e) {
            const float kxe = fmaxf(ax[e], 0.f);  // relu(k)
            const float kye = fmaxf(ay[e], 0.f);
#pragma unroll
            for (int d = 0; d < 8; ++d) {
                kvf[d * 8 + e] = fmaf(ax[8 + d], kxe, kvf[d * 8 + e]);  // v (no relu)
                kvf[d * 8 + e] = fmaf(ay[8 + d], kye, kvf[d * 8 + e]);
            }
            kvf[64 + e] += kxe + kye;  // ones-row
        }
    }

    // wave64 butterfly reduction of all 72 partials
#pragma unroll
    for (int i = 0; i < 72; ++i) {
        float v = kvf[i];
        v += __shfl_xor(v, 1);
        v += __shfl_xor(v, 2);
        v += __shfl_xor(v, 4);
        v += __shfl_xor(v, 8);
        v += __shfl_xor(v, 16);
        v += __shfl_xor(v, 32);
        kvf[i] = v;
    }
    if ((tid & 63) == 0) {
        float* dst = kv_g + b * 72;
#pragma unroll
        for (int i = 0; i < 72; ++i) atomicAdd(dst + i, kvf[i]);
    }
}

__global__ __launch_bounds__(64) void a_mat_kernel(
    const float* __restrict__ proj_w, const float* __restrict__ kv_g,
    float* __restrict__ a_g)
{
    const int b = blockIdx.x;
    const int c = threadIdx.x;
    float pw[8];
#pragma unroll
    for (int d = 0; d < 8; ++d) pw[d] = proj_w[c * 8 + d];
    const float* kv = kv_g + b * 72;
#pragma unroll
    for (int e = 0; e < 8; ++e) {
        float s = 0.f;
#pragma unroll
        for (int d = 0; d < 8; ++d) s = fmaf(pw[d], kv[d * 8 + e], s);
        a_g[b * 512 + c * 8 + e] = s;
    }
}

__global__ __launch_bounds__(256) void out_kernel(
    const float* __restrict__ x, const float* __restrict__ qkv_w,
    const float* __restrict__ kv_g, const float* __restrict__ a_g,
    float* __restrict__ out)
{
    const int b = blockIdx.x >> 8;                       // 256 blocks per batch
    const int n = ((blockIdx.x & 255) << 8) | threadIdx.x;
    const float* xb = x + (size_t)b * C_CH * N_PIX + n;
    float* ob = out + (size_t)b * C_CH * N_PIX + n;

    float xv[64];  // fully unrolled -> stays in VGPRs
    float q[8] = {0.f, 0.f, 0.f, 0.f, 0.f, 0.f, 0.f, 0.f};
#pragma unroll
    for (int c = 0; c < 64; ++c) {
        xv[c] = xb[(size_t)c * N_PIX];
#pragma unroll
        for (int e = 0; e < 8; ++e)
            q[e] = fmaf(qkv_w[e * 64 + c], xv[c], q[e]);  // uniform weights
    }
    float den = EPS_F;
#pragma unroll
    for (int e = 0; e < 8; ++e) {
        q[e] = fmaxf(q[e], 0.f);                          // relu(q)
        den = fmaf(kv_g[b * 72 + 64 + e], q[e], den);     // kv[8][e] row
    }
    const float inv = 1.0f / den;  // den >= eps > 0 (k,q >= 0)
    float qs[8];
#pragma unroll
    for (int e = 0; e < 8; ++e) qs[e] = q[e] * inv;

    const float* Ab = a_g + b * 512;
#pragma unroll
    for (int c = 0; c < 64; ++c) {
        float s = xv[c];
#pragma unroll
        for (int e = 0; e < 8; ++e) s = fmaf(Ab[c * 8 + e], qs[e], s);
        ob[(size_t)c * N_PIX] = s;
    }
}

extern "C" void kernel_launch(void* const* d_in, const int* in_sizes, int n_in,
                              void* d_out, int out_size, void* d_ws, size_t ws_size,
                              hipStream_t stream)
{
    const float* x = (const float*)d_in[0];
    const float* qkv_w = (const float*)d_in[1];
    const float* proj_w = (const float*)d_in[2];
    float* out = (float*)d_out;

    float* kv_g = (float*)d_ws;             // 16*72 floats
    float* a_g = (float*)d_ws + 16 * 72;    // 16*512 floats

    hipMemsetAsync(d_ws, 0, 16 * 72 * sizeof(float), stream);
    kv_reduce_kernel<<<1024, 256, 0, stream>>>(x, qkv_w, kv_g);
    a_mat_kernel<<<16, 64, 0, stream>>>(proj_w, kv_g, a_g);
    out_kernel<<<4096, 256, 0, stream>>>(x, qkv_w, kv_g, a_g, out);
}